// Round 1
// baseline (716.914 us; speedup 1.0000x reference)
//
#include <hip/hip_runtime.h>
#include <stdint.h>

typedef __attribute__((ext_vector_type(8))) short short8;
typedef __attribute__((ext_vector_type(4))) float floatx4;

__device__ inline unsigned short f2bf(float f){
  union { float fv; unsigned int u; } v; v.fv = f;
  unsigned int u = v.u;
  unsigned int r = ((u >> 16) & 1u) + 0x7FFFu;
  return (unsigned short)((u + r) >> 16);
}

// ---------------- weight prep (reindex/transpose) ----------------
// w_s1 [192][3][7][7] -> w1t[(c*49+ky*7+kx)*192 + o]  (fp32)
__global__ void prep_w1(const float* __restrict__ w, float* __restrict__ w1t){
  int i = blockIdx.x*256 + threadIdx.x;
  if (i >= 147*192) return;
  int o = i % 192, r = i / 192;
  w1t[i] = w[o*147 + r];
}
// w_s2 [192][192][7][7] -> w2p[o][(ky*7+kx)*192 + c]  (bf16)  == B^T rows of K=9408
__global__ void prep_w2(const float* __restrict__ w, unsigned short* __restrict__ w2p){
  int i = blockIdx.x*256 + threadIdx.x;
  if (i >= 192*9408) return;
  int k = i % 9408, o = i / 9408;
  int g = k / 192, c = k % 192;
  int ky = g / 7, kx = g % 7;
  w2p[i] = f2bf(w[((o*192 + c)*7 + ky)*7 + kx]);
}
// w_p [768][960][3][3] -> w3p[o][(ky*3+kx)*960 + c]  (bf16)  == B^T rows of K=8640
__global__ void prep_w3(const float* __restrict__ w, unsigned short* __restrict__ w3p){
  int i = blockIdx.x*256 + threadIdx.x;
  if (i >= 768*8640) return;
  int k = i % 8640, o = i / 8640;
  int g = k / 960, c = k % 960;
  int ky = g / 3, kx = g % 3;
  w3p[i] = f2bf(w[((o*960 + c)*3 + ky)*3 + kx]);
}

// ---------------- wavelet: per 16x16 block 2D WHT / 16 ----------------
// out channel = k*3 + c, k's base-4 digits d1..d4 (d1 = level 1) map to
// WHT index m = mask_r*16 + mask_c, mask bit (i-1) = digit_i's row/col diff bit.
__global__ void wavelet_kernel(const float* __restrict__ x, unsigned short* __restrict__ feat){
  int blk = blockIdx.x;
  int j = blk % 14; blk /= 14;
  int i = blk % 14; blk /= 14;
  int c = blk % 3;  int b = blk / 3;
  int t = threadIdx.x;
  int u = t >> 4, v = t & 15;
  __shared__ float s[256];
  float val = x[((size_t)(b*3 + c)*224 + (i*16 + u))*224 + (j*16 + v)];
  s[t] = val; __syncthreads();
  #pragma unroll
  for (int bit = 1; bit < 256; bit <<= 1){
    float p = s[t ^ bit];
    val = (t & bit) ? (p - val) : (val + p);
    __syncthreads();
    s[t] = val;
    __syncthreads();
  }
  int k = t;
  int d1 = (k>>6)&3, d2 = (k>>4)&3, d3 = (k>>2)&3, d4 = k&3;
  int mr = (d1>>1) | ((d2>>1)<<1) | ((d3>>1)<<2) | ((d4>>1)<<3);
  int mc = (d1&1)  | ((d2&1)<<1)  | ((d3&1)<<2)  | ((d4&1)<<3);
  float outv = s[mr*16 + mc] * 0.0625f;
  feat[((size_t)((b*14 + i)*14 + j))*960 + (k*3 + c)] = f2bf(outv);
}

// ---------------- conv1: 3->192, 7x7 s4 p3, 224->56, VALU direct ----------------
// block = 192 threads (thread = out channel), covers one (b, y, 14 x's)
__global__ __launch_bounds__(192) void conv1_kernel(const float* __restrict__ x,
                                                    const float* __restrict__ w1t,
                                                    const float* __restrict__ b1,
                                                    unsigned short* __restrict__ sp1){
  int blk = blockIdx.x;
  int xt = blk % 4; blk /= 4;
  int y = blk % 56; int b = blk / 56;
  int o = threadIdx.x;
  __shared__ float patch[3*7*60]; // [c][ky][col<59], col = 4*xl + kx, base ix = 56*xt-3
  for (int idx = o; idx < 3*7*60; idx += 192){
    int col = idx % 60; int rem = idx / 60;
    int ky = rem % 7;   int c = rem / 7;
    int iy = 4*y - 3 + ky;
    int ix = 56*xt - 3 + col;
    float vv = 0.f;
    if (col < 59 && iy >= 0 && iy < 224 && ix >= 0 && ix < 224)
      vv = x[((size_t)(b*3 + c)*224 + iy)*224 + ix];
    patch[idx] = vv;
  }
  __syncthreads();
  float acc[14];
  float bias = b1[o];
  #pragma unroll
  for (int i = 0; i < 14; i++) acc[i] = bias;
  for (int c = 0; c < 3; c++){
    for (int ky = 0; ky < 7; ky++){
      const float* prow = &patch[(c*7 + ky)*60];
      #pragma unroll
      for (int kx = 0; kx < 7; kx++){
        float w = w1t[(c*49 + ky*7 + kx)*192 + o];
        #pragma unroll
        for (int i = 0; i < 14; i++)
          acc[i] = fmaf(w, prow[4*i + kx], acc[i]);
      }
    }
  }
  for (int i = 0; i < 14; i++){
    int xx = 14*xt + i;
    sp1[((size_t)((b*56 + y)*56 + xx))*192 + o] = f2bf(acc[i]);
  }
}

// ---------------- implicit-GEMM conv, bf16 MFMA 16x16x32 ----------------
// C[M,N] = A[M,K] x B[K,N]; A gathered from NHWC activations, Bt pre-transposed [N][K].
// BM=BN=64, BK=64, 256 threads = 4 waves in 2x2, each wave 32x32 (2x2 MFMA tiles).
template<int MODE>
__global__ __launch_bounds__(256) void conv_gemm(const unsigned short* __restrict__ Ain,
                                                 const unsigned short* __restrict__ Bt,
                                                 const float* __restrict__ bias,
                                                 const float* __restrict__ pos,
                                                 void* __restrict__ outp){
  constexpr int OH  = (MODE==2) ? 14 : 7;
  constexpr int OW  = OH;
  constexpr int IH  = (MODE==2) ? 56 : 14;
  constexpr int IW  = IH;
  constexpr int Cin = (MODE==2) ? 192 : 960;
  constexpr int KW  = (MODE==2) ? 7 : 3;
  constexpr int S   = (MODE==2) ? 4 : 2;
  constexpr int P   = (MODE==2) ? 3 : 1;
  constexpr int K   = (MODE==2) ? 9408 : 8640;
  constexpr int LDK = 88; // 64 + 24 pad: 16B-aligned rows, 2-way max bank conflict

  int m0 = blockIdx.x * 64;
  int n0 = blockIdx.y * 64;
  int tid  = threadIdx.x;
  int wave = tid >> 6, lane = tid & 63;
  int l16 = lane & 15, quad = lane >> 4;
  int wy = wave >> 1, wx = wave & 1;

  __shared__ unsigned short As[64][LDK];
  __shared__ unsigned short Bs[64][LDK];

  floatx4 acc[2][2];
  #pragma unroll
  for (int a = 0; a < 2; a++)
    #pragma unroll
    for (int bq = 0; bq < 2; bq++)
      acc[a][bq] = (floatx4){0.f,0.f,0.f,0.f};

  // staging role: thread stages row ar of A-tile and B-tile, 2x16B each
  int ar = tid >> 2;
  int apart = (tid & 3) * 8;
  int m = m0 + ar;
  int ox = m % OW; int t2 = m / OW; int oy = t2 % OH; int bb = t2 / OH;

  const unsigned short* brow = Bt + (size_t)(n0 + ar) * K + apart;

  int g = 0, c0 = 0, ky = 0, kx = 0;
  for (int k0 = 0; k0 < K; k0 += 64){
    int iy = S*oy - P + ky;
    int ix = S*ox - P + kx;
    uint4 a0 = make_uint4(0u,0u,0u,0u), a1 = a0;
    if (iy >= 0 && iy < IH && ix >= 0 && ix < IW){
      const unsigned short* abase = Ain + ((size_t)((bb*IH + iy)*IW + ix))*Cin + c0 + apart;
      a0 = *(const uint4*)abase;
      a1 = *(const uint4*)(abase + 32);
    }
    uint4 b0 = *(const uint4*)(brow + k0);
    uint4 b1 = *(const uint4*)(brow + k0 + 32);

    __syncthreads();
    *(uint4*)&As[ar][apart]      = a0;
    *(uint4*)&As[ar][apart + 32] = a1;
    *(uint4*)&Bs[ar][apart]      = b0;
    *(uint4*)&Bs[ar][apart + 32] = b1;
    __syncthreads();

    #pragma unroll
    for (int ks = 0; ks < 2; ks++){
      short8 af0 = *(const short8*)&As[wy*32      + l16][ks*32 + quad*8];
      short8 af1 = *(const short8*)&As[wy*32 + 16 + l16][ks*32 + quad*8];
      short8 bf0 = *(const short8*)&Bs[wx*32      + l16][ks*32 + quad*8];
      short8 bf1 = *(const short8*)&Bs[wx*32 + 16 + l16][ks*32 + quad*8];
      acc[0][0] = __builtin_amdgcn_mfma_f32_16x16x32_bf16(af0, bf0, acc[0][0], 0, 0, 0);
      acc[0][1] = __builtin_amdgcn_mfma_f32_16x16x32_bf16(af0, bf1, acc[0][1], 0, 0, 0);
      acc[1][0] = __builtin_amdgcn_mfma_f32_16x16x32_bf16(af1, bf0, acc[1][0], 0, 0, 0);
      acc[1][1] = __builtin_amdgcn_mfma_f32_16x16x32_bf16(af1, bf1, acc[1][1], 0, 0, 0);
    }

    // advance (g, c0) -> (ky, kx)
    c0 += 64;
    if (c0 == Cin){ c0 = 0; g++; kx++; if (kx == KW){ kx = 0; ky++; } }
  }

  // epilogue: C/D layout col=lane&15, row=quad*4+reg
  #pragma unroll
  for (int mt = 0; mt < 2; mt++){
    #pragma unroll
    for (int nt = 0; nt < 2; nt++){
      #pragma unroll
      for (int rg = 0; rg < 4; rg++){
        int row = wy*32 + mt*16 + quad*4 + rg;
        int col = wx*32 + nt*16 + l16;
        int mm = m0 + row, nn = n0 + col;
        float v = acc[mt][nt][rg] + bias[nn];
        int ox2 = mm % OW; int tt2 = mm / OW; int oy2 = tt2 % OH; int bb2 = tt2 / OH;
        if (MODE == 2){
          ((unsigned short*)outp)[((size_t)((bb2*14 + oy2)*14 + ox2))*960 + 768 + nn] = f2bf(v);
        } else {
          int tt = oy2*7 + ox2;
          v += pos[(size_t)(1 + tt)*768 + nn];
          ((float*)outp)[((size_t)(bb2*50 + 1 + tt))*768 + nn] = v;
        }
      }
    }
  }
}

// ---------------- cls row ----------------
__global__ void cls_kernel(const float* __restrict__ cls, const float* __restrict__ pos,
                           float* __restrict__ out){
  int i = blockIdx.x*256 + threadIdx.x;
  if (i >= 64*768) return;
  int e = i % 768, b = i / 768;
  out[(size_t)(b*50)*768 + e] = cls[e] + pos[e];
}

extern "C" void kernel_launch(void* const* d_in, const int* in_sizes, int n_in,
                              void* d_out, int out_size, void* d_ws, size_t ws_size,
                              hipStream_t stream){
  (void)in_sizes; (void)n_in; (void)out_size;
  const float* x    = (const float*)d_in[0];
  const float* w_s1 = (const float*)d_in[1];
  const float* b_s1 = (const float*)d_in[2];
  const float* w_s2 = (const float*)d_in[3];
  const float* b_s2 = (const float*)d_in[4];
  const float* w_p  = (const float*)d_in[5];
  const float* b_p  = (const float*)d_in[6];
  const float* cls  = (const float*)d_in[7];
  const float* pos  = (const float*)d_in[8];
  float* out = (float*)d_out;

  char* ws = (char*)d_ws;
  // ws layout (bytes):
  //   w1t  fp32 @ 0          (112,896 B)
  //   w2p  bf16 @ 131072     (3,612,672 B)
  //   w3p  bf16 @ 4194304    (13,271,040 B)
  //   sp1  bf16 NHWC 64x56x56x192 @ 17825792  (77,070,336 B)
  //   feat bf16 NHWC 64x14x14x960 @ 95420416  (24,084,480 B)  -> total 119,504,896 B
  if (ws_size < 119504896u) return;
  float*          w1t  = (float*)(ws + 0);
  unsigned short* w2p  = (unsigned short*)(ws + 131072);
  unsigned short* w3p  = (unsigned short*)(ws + 4194304);
  unsigned short* sp1  = (unsigned short*)(ws + 17825792);
  unsigned short* feat = (unsigned short*)(ws + 95420416);

  prep_w1<<<(147*192 + 255)/256, 256, 0, stream>>>(w_s1, w1t);
  prep_w2<<<(192*9408 + 255)/256, 256, 0, stream>>>(w_s2, w2p);
  prep_w3<<<(768*8640 + 255)/256, 256, 0, stream>>>(w_p, w3p);
  wavelet_kernel<<<64*3*14*14, 256, 0, stream>>>(x, feat);
  conv1_kernel<<<64*56*4, 192, 0, stream>>>(x, w1t, b_s1, sp1);
  conv_gemm<2><<<dim3(12544/64, 192/64), 256, 0, stream>>>(sp1, w2p, b_s2, nullptr, (void*)feat);
  conv_gemm<3><<<dim3(3136/64, 768/64), 256, 0, stream>>>(feat, w3p, b_p, pos, (void*)out);
  cls_kernel<<<(64*768 + 255)/256, 256, 0, stream>>>(cls, pos, out);
}

// Round 2
// 429.012 us; speedup vs baseline: 1.6711x; 1.6711x over previous
//
#include <hip/hip_runtime.h>
#include <stdint.h>

typedef __attribute__((ext_vector_type(8))) short short8;
typedef __attribute__((ext_vector_type(4))) float floatx4;

__device__ inline unsigned short f2bf(float f){
  union { float fv; unsigned int u; } v; v.fv = f;
  unsigned int u = v.u;
  unsigned int r = ((u >> 16) & 1u) + 0x7FFFu;
  return (unsigned short)((u + r) >> 16);
}

// async global->LDS, 16B per lane, dest = wave-uniform base + lane*16
__device__ __forceinline__ void async16(const void* g, void* l){
  __builtin_amdgcn_global_load_lds(
      (const __attribute__((address_space(1))) unsigned int*)g,
      (__attribute__((address_space(3))) unsigned int*)l, 16, 0, 0);
}

// ---------------- weight prep ----------------
// w_s1 [192][3][7][7] -> w1p[o][k], k = (c*7+ky)*8 + kx (kx padded to 8), K'=192, zero pad
__global__ void prep_w1(const float* __restrict__ w, unsigned short* __restrict__ w1p){
  int i = blockIdx.x*256 + threadIdx.x;
  if (i >= 192*192) return;
  int k = i % 192, o = i / 192;
  int cc = k >> 3, kx = k & 7;
  unsigned short v = 0;
  if (cc < 21 && kx < 7){
    int c = cc / 7, ky = cc % 7;
    v = f2bf(w[(o*3 + c)*49 + ky*7 + kx]);
  }
  w1p[i] = v;
}
// w_s2 [192][192][7][7] -> w2p[o][(ky*7+kx)*192 + c]  (B^T rows, K=9408)
__global__ void prep_w2(const float* __restrict__ w, unsigned short* __restrict__ w2p){
  int i = blockIdx.x*256 + threadIdx.x;
  if (i >= 192*9408) return;
  int k = i % 9408, o = i / 9408;
  int g = k / 192, c = k % 192;
  int ky = g / 7, kx = g % 7;
  w2p[i] = f2bf(w[((o*192 + c)*7 + ky)*7 + kx]);
}
// w_p [768][960][3][3] -> w3p[o][(ky*3+kx)*960 + c]  (B^T rows, K=8640)
__global__ void prep_w3(const float* __restrict__ w, unsigned short* __restrict__ w3p){
  int i = blockIdx.x*256 + threadIdx.x;
  if (i >= 768*8640) return;
  int k = i % 8640, o = i / 8640;
  int g = k / 960, c = k % 960;
  int ky = g / 3, kx = g % 3;
  w3p[i] = f2bf(w[((o*960 + c)*3 + ky)*3 + kx]);
}
// zero page for OOB global_load_lds redirect (ws is re-poisoned 0xAA every call)
__global__ void prep_zp(unsigned int* __restrict__ zp){
  zp[threadIdx.x] = 0u;  // 64 threads * 4 B = 256 B
}

// ---------------- pad x: NCHW f32 [64][3][224][224] -> bf16 [64][3][230][232], 3-pad ----------------
__global__ void pad_x(const float* __restrict__ x, unsigned short* __restrict__ xh){
  int idx = blockIdx.x*256 + threadIdx.x;
  if (idx >= 64*3*230*232) return;
  int px = idx % 232; int t = idx / 232;
  int py = t % 230;   t /= 230;          // t = b*3 + c
  unsigned short v = 0;
  if (py >= 3 && py < 227 && px >= 3 && px < 227)
    v = f2bf(x[((size_t)t*224 + (py-3))*224 + (px-3)]);
  xh[idx] = v;
}

// ---------------- wavelet: per 16x16 block 2D WHT / 16 (shfl butterfly) ----------------
__global__ void wavelet_kernel(const float* __restrict__ x, unsigned short* __restrict__ feat){
  int blk = blockIdx.x;
  int j = blk % 14; blk /= 14;
  int i = blk % 14; blk /= 14;
  int c = blk % 3;  int b = blk / 3;
  int t = threadIdx.x;
  int u = t >> 4, v = t & 15;
  float val = x[((size_t)(b*3 + c)*224 + (i*16 + u))*224 + (j*16 + v)];
  #pragma unroll
  for (int bit = 1; bit < 64; bit <<= 1){
    float p = __shfl_xor(val, bit);
    val = (t & bit) ? (p - val) : (val + p);
  }
  __shared__ float s[256];
  #pragma unroll
  for (int bit = 64; bit < 256; bit <<= 1){
    s[t] = val; __syncthreads();
    float p = s[t ^ bit]; __syncthreads();
    val = (t & bit) ? (p - val) : (val + p);
  }
  s[t] = val; __syncthreads();
  int k = t;
  int d1 = (k>>6)&3, d2 = (k>>4)&3, d3 = (k>>2)&3, d4 = k&3;
  int mr = (d1>>1) | ((d2>>1)<<1) | ((d3>>1)<<2) | ((d4>>1)<<3);
  int mc = (d1&1)  | ((d2&1)<<1)  | ((d3&1)<<2)  | ((d4&1)<<3);
  float outv = s[mr*16 + mc] * 0.0625f;
  feat[((size_t)((b*14 + i)*14 + j))*960 + (k*3 + c)] = f2bf(outv);
}

// ---------------- conv1 as single-shot MFMA GEMM: M=200704, N=192, K'=192 ----------------
__global__ __launch_bounds__(256) void conv1_gemm(const unsigned short* __restrict__ xh,
                                                  const unsigned short* __restrict__ w1p,
                                                  const float* __restrict__ b1,
                                                  unsigned short* __restrict__ sp1){
  constexpr int LDK = 200;
  __shared__ unsigned short As[64*LDK], Bs[64*LDK];
  int m0 = blockIdx.x*64, n0 = blockIdx.y*64;
  int tid = threadIdx.x;
  // stage B (w1p rows, fully padded/aligned)
  #pragma unroll
  for (int i = 0; i < 6; i++){
    int id = tid + i*256; int row = id/24, cc = id%24;
    *(uint4*)&Bs[row*LDK + cc*8] = *(const uint4*)&w1p[(n0+row)*192 + cc*8];
  }
  // stage A (implicit im2col gather from padded xh; 8B-aligned pairs)
  #pragma unroll
  for (int i = 0; i < 6; i++){
    int id = tid + i*256; int row = id/24, cc = id%24;
    int m = m0 + row; int ox = m % 56; int t = m / 56; int oy = t % 56; int b = t / 56;
    uint2 v0 = make_uint2(0u,0u), v1 = v0;
    if (cc < 21){
      int c = cc / 7, ky = cc % 7;
      const unsigned short* p = xh + ((size_t)((b*3 + c)*230 + 4*oy + ky))*232 + 4*ox;
      v0 = *(const uint2*)p;
      v1 = *(const uint2*)(p + 4);
    }
    *(uint2*)&As[row*LDK + cc*8]     = v0;
    *(uint2*)&As[row*LDK + cc*8 + 4] = v1;
  }
  __syncthreads();
  int lane = tid & 63, wave = tid >> 6;
  int l16 = lane & 15, quad = lane >> 4;
  int wy = wave >> 1, wx = wave & 1;
  floatx4 acc[2][2];
  #pragma unroll
  for (int a = 0; a < 2; a++)
    #pragma unroll
    for (int bq = 0; bq < 2; bq++) acc[a][bq] = (floatx4){0.f,0.f,0.f,0.f};
  #pragma unroll
  for (int ks = 0; ks < 6; ks++){
    short8 a0 = *(const short8*)&As[(wy*32      + l16)*LDK + ks*32 + quad*8];
    short8 a1 = *(const short8*)&As[(wy*32 + 16 + l16)*LDK + ks*32 + quad*8];
    short8 b0 = *(const short8*)&Bs[(wx*32      + l16)*LDK + ks*32 + quad*8];
    short8 b1 = *(const short8*)&Bs[(wx*32 + 16 + l16)*LDK + ks*32 + quad*8];
    acc[0][0] = __builtin_amdgcn_mfma_f32_16x16x32_bf16(a0, b0, acc[0][0], 0, 0, 0);
    acc[0][1] = __builtin_amdgcn_mfma_f32_16x16x32_bf16(a0, b1, acc[0][1], 0, 0, 0);
    acc[1][0] = __builtin_amdgcn_mfma_f32_16x16x32_bf16(a1, b0, acc[1][0], 0, 0, 0);
    acc[1][1] = __builtin_amdgcn_mfma_f32_16x16x32_bf16(a1, b1, acc[1][1], 0, 0, 0);
  }
  #pragma unroll
  for (int mt = 0; mt < 2; mt++){
    #pragma unroll
    for (int rg = 0; rg < 4; rg++){
      int row = wy*32 + mt*16 + quad*4 + rg;
      int mm = m0 + row;
      int ox = mm % 56; int t2 = mm / 56; int oy = t2 % 56; int bb = t2 / 56;
      size_t obase = ((size_t)((bb*56 + oy)*56 + ox))*192;
      #pragma unroll
      for (int nt = 0; nt < 2; nt++){
        int nn = n0 + wx*32 + nt*16 + l16;
        sp1[obase + nn] = f2bf(acc[mt][nt][rg] + b1[nn]);
      }
    }
  }
}

// ---------------- implicit-GEMM conv, bf16 MFMA, global_load_lds + XOR swizzle ----------------
// BM=BN=64, BK=64, 4 waves 2x2 (wave 32x32). LDS unpadded [64][64] with 16B-chunk
// swizzle kb' = kb ^ (row&7). OOB A rows redirect to zero page.
template<int MODE>
__global__ __launch_bounds__(256) void conv_gemm(const unsigned short* __restrict__ Ain,
                                                 const unsigned short* __restrict__ Bt,
                                                 const float* __restrict__ bias,
                                                 const float* __restrict__ pos,
                                                 const unsigned short* __restrict__ zp,
                                                 void* __restrict__ outp){
  constexpr int OH  = (MODE==2) ? 14 : 7;
  constexpr int OW  = OH;
  constexpr int IH  = (MODE==2) ? 56 : 14;
  constexpr int IW  = IH;
  constexpr int Cin = (MODE==2) ? 192 : 960;
  constexpr int KW  = (MODE==2) ? 7 : 3;
  constexpr int S   = (MODE==2) ? 4 : 2;
  constexpr int P   = (MODE==2) ? 3 : 1;
  constexpr int K   = (MODE==2) ? 9408 : 8640;
  constexpr int MTI = (MODE==2) ? 196 : 49;   // m-tiles
  constexpr int GRP = (MODE==2) ? 24 : 96;    // 8 XCD slots * n-tiles

  // XCD swizzle: the n-tiles of one m-tile land on the same XCD (id%8), close in time
  int id = blockIdx.x;
  int g = id / GRP, rem = id % GRP;
  int mtile = g*8 + (rem & 7), ntile = rem >> 3;
  if (mtile >= MTI) return;
  int m0 = mtile*64, n0 = ntile*64;

  __shared__ unsigned short As[64*64], Bs[64*64];
  int tid = threadIdx.x, wave = tid >> 6, lane = tid & 63;
  int l16 = lane & 15, quad = lane >> 4;
  int wy = wave >> 1, wx = wave & 1;

  // staging roles: lane -> (row-in-8-group, swizzled chunk)
  int r8 = lane >> 3, kb7 = lane & 7;
  int kb = kb7 ^ r8;                 // global 8-elem chunk this lane fetches
  int rA0 = wave*16 + r8, rA1 = rA0 + 8;

  // A-row geometry (fixed per lane across K loop)
  int m_0 = m0 + rA0;
  int ox0 = m_0 % OW; int t0 = m_0 / OW; int oy0 = t0 % OH; int bb0 = t0 / OH;
  int iyb0 = S*oy0 - P, ixb0 = S*ox0 - P;
  int abase0 = ((bb0*IH + iyb0)*IW + ixb0)*Cin + kb*8;
  int m_1 = m0 + rA1;
  int ox1 = m_1 % OW; int t1 = m_1 / OW; int oy1 = t1 % OH; int bb1 = t1 / OH;
  int iyb1 = S*oy1 - P, ixb1 = S*ox1 - P;
  int abase1 = ((bb1*IH + iyb1)*IW + ixb1)*Cin + kb*8;

  const unsigned short* pB0 = Bt + (size_t)(n0 + rA0)*K + kb*8;
  const unsigned short* pB1 = Bt + (size_t)(n0 + rA1)*K + kb*8;

  // wave-uniform LDS staging bases (1 KB per call: 8 rows x 64 elems)
  void* dA0 = (void*)&As[(wave*16    )*64];
  void* dA1 = (void*)&As[(wave*16 + 8)*64];
  void* dB0 = (void*)&Bs[(wave*16    )*64];
  void* dB1 = (void*)&Bs[(wave*16 + 8)*64];

  // fragment swizzled chunk offsets (constants per lane; frag row&7 == l16&7)
  int sw = l16 & 7;
  int x0 = ((0 + quad) ^ sw) * 8;
  int x1 = ((4 + quad) ^ sw) * 8;
  int aoff0 = (wy*32      + l16)*64;
  int aoff1 = (wy*32 + 16 + l16)*64;
  int boff0 = (wx*32      + l16)*64;
  int boff1 = (wx*32 + 16 + l16)*64;

  floatx4 acc[2][2];
  #pragma unroll
  for (int a = 0; a < 2; a++)
    #pragma unroll
    for (int bq = 0; bq < 2; bq++) acc[a][bq] = (floatx4){0.f,0.f,0.f,0.f};

  int c0 = 0, ky = 0, kx = 0;
  for (int k0 = 0; k0 < K; k0 += 64){
    int koff = (ky*IW + kx)*Cin + c0;
    int iy0 = iyb0 + ky, ix0 = ixb0 + kx;
    int iy1 = iyb1 + ky, ix1 = ixb1 + kx;
    const unsigned short* pa0 = ((unsigned)iy0 < (unsigned)IH && (unsigned)ix0 < (unsigned)IW)
                                ? (Ain + (abase0 + koff)) : zp;
    const unsigned short* pa1 = ((unsigned)iy1 < (unsigned)IH && (unsigned)ix1 < (unsigned)IW)
                                ? (Ain + (abase1 + koff)) : zp;
    __syncthreads();
    async16(pa0, dA0);
    async16(pa1, dA1);
    async16(pB0 + k0, dB0);
    async16(pB1 + k0, dB1);
    __syncthreads();

    #pragma unroll
    for (int ks = 0; ks < 2; ks++){
      int xo = ks ? x1 : x0;
      short8 a0 = *(const short8*)&As[aoff0 + xo];
      short8 a1 = *(const short8*)&As[aoff1 + xo];
      short8 b0 = *(const short8*)&Bs[boff0 + xo];
      short8 b1 = *(const short8*)&Bs[boff1 + xo];
      acc[0][0] = __builtin_amdgcn_mfma_f32_16x16x32_bf16(a0, b0, acc[0][0], 0, 0, 0);
      acc[0][1] = __builtin_amdgcn_mfma_f32_16x16x32_bf16(a0, b1, acc[0][1], 0, 0, 0);
      acc[1][0] = __builtin_amdgcn_mfma_f32_16x16x32_bf16(a1, b0, acc[1][0], 0, 0, 0);
      acc[1][1] = __builtin_amdgcn_mfma_f32_16x16x32_bf16(a1, b1, acc[1][1], 0, 0, 0);
    }

    c0 += 64;
    if (c0 == Cin){ c0 = 0; kx++; if (kx == KW){ kx = 0; ky++; } }
  }

  #pragma unroll
  for (int mt = 0; mt < 2; mt++){
    #pragma unroll
    for (int rg = 0; rg < 4; rg++){
      int row = wy*32 + mt*16 + quad*4 + rg;
      int mm = m0 + row;
      int ox2 = mm % OW; int t2 = mm / OW; int oy2 = t2 % OH; int bb2 = t2 / OH;
      #pragma unroll
      for (int nt = 0; nt < 2; nt++){
        int nn = n0 + wx*32 + nt*16 + l16;
        float v = acc[mt][nt][rg] + bias[nn];
        if (MODE == 2){
          ((unsigned short*)outp)[((size_t)((bb2*14 + oy2)*14 + ox2))*960 + 768 + nn] = f2bf(v);
        } else {
          int tt = oy2*7 + ox2;
          v += pos[(size_t)(1 + tt)*768 + nn];
          ((float*)outp)[((size_t)(bb2*50 + 1 + tt))*768 + nn] = v;
        }
      }
    }
  }
}

// ---------------- cls row ----------------
__global__ void cls_kernel(const float* __restrict__ cls, const float* __restrict__ pos,
                           float* __restrict__ out){
  int i = blockIdx.x*256 + threadIdx.x;
  if (i >= 64*768) return;
  int e = i % 768, b = i / 768;
  out[(size_t)(b*50)*768 + e] = cls[e] + pos[e];
}

extern "C" void kernel_launch(void* const* d_in, const int* in_sizes, int n_in,
                              void* d_out, int out_size, void* d_ws, size_t ws_size,
                              hipStream_t stream){
  (void)in_sizes; (void)n_in; (void)out_size;
  const float* x    = (const float*)d_in[0];
  const float* w_s1 = (const float*)d_in[1];
  const float* b_s1 = (const float*)d_in[2];
  const float* w_s2 = (const float*)d_in[3];
  const float* b_s2 = (const float*)d_in[4];
  const float* w_p  = (const float*)d_in[5];
  const float* b_p  = (const float*)d_in[6];
  const float* cls  = (const float*)d_in[7];
  const float* pos  = (const float*)d_in[8];
  float* out = (float*)d_out;

  char* ws = (char*)d_ws;
  // ws layout (bytes):
  //   w1p bf16 [192][192]            @ 0          (73,728)
  //   w2p bf16 [192][9408]           @ 131072     (3,612,672)
  //   w3p bf16 [768][8640]           @ 4194304    (13,271,040)
  //   sp1 bf16 NHWC [64][56][56][192]@ 17825792   (77,070,336)
  //   zp  256 B zero page            @ 94896128
  //   feat bf16 NHWC [64][14][14][960] @ 95420416 (24,084,480)
  //   xh  bf16 [64][3][230][232] ALIASES feat (20,490,240 <= 24,084,480);
  //       ordering: pad_x -> conv1_gemm (reads xh) -> wavelet/conv2 (write feat)
  if (ws_size < 119504896u) return;
  unsigned short* w1p  = (unsigned short*)(ws + 0);
  unsigned short* w2p  = (unsigned short*)(ws + 131072);
  unsigned short* w3p  = (unsigned short*)(ws + 4194304);
  unsigned short* sp1  = (unsigned short*)(ws + 17825792);
  unsigned short* zp   = (unsigned short*)(ws + 94896128);
  unsigned short* feat = (unsigned short*)(ws + 95420416);
  unsigned short* xh   = feat;

  prep_w1<<<(192*192 + 255)/256, 256, 0, stream>>>(w_s1, w1p);
  prep_w2<<<(192*9408 + 255)/256, 256, 0, stream>>>(w_s2, w2p);
  prep_w3<<<(768*8640 + 255)/256, 256, 0, stream>>>(w_p, w3p);
  prep_zp<<<1, 64, 0, stream>>>((unsigned int*)zp);
  pad_x<<<(64*3*230*232)/256, 256, 0, stream>>>(x, xh);
  conv1_gemm<<<dim3(3136, 3), 256, 0, stream>>>(xh, w1p, b_s1, sp1);
  wavelet_kernel<<<64*3*14*14, 256, 0, stream>>>(x, feat);
  conv_gemm<2><<<600, 256, 0, stream>>>(sp1, w2p, b_s2, nullptr, zp, (void*)feat);
  conv_gemm<3><<<672, 256, 0, stream>>>(feat, w3p, b_p, pos, zp, (void*)out);
  cls_kernel<<<(64*768 + 255)/256, 256, 0, stream>>>(cls, pos, out);
}